// Round 8
// baseline (59.520 us; speedup 1.0000x reference)
//
#include <hip/hip_runtime.h>

#define BATCH 4
#define SEQ   4096
#define EMB   1024
#define HD    64
#define NROW  (BATCH*SEQ)

typedef float f32x4  __attribute__((ext_vector_type(4)));
typedef short bf16x8 __attribute__((ext_vector_type(8)));
typedef short bf16x4 __attribute__((ext_vector_type(4)));

#define LOG2E 1.4426950408889634f
#define EXP2(x) exp2f(x)

static __device__ __forceinline__ f32x4 MFMA16(bf16x4 a, bf16x4 b, f32x4 c) {
#if defined(__HIP_DEVICE_COMPILE__) && __has_builtin(__builtin_amdgcn_mfma_f32_16x16x16bf16_1k)
  return __builtin_amdgcn_mfma_f32_16x16x16bf16_1k(a, b, c, 0, 0, 0);
#elif defined(__HIP_DEVICE_COMPILE__)
  f32x4 d;
  asm volatile("v_mfma_f32_16x16x16_bf16 %0, %1, %2, %3"
               : "=v"(d) : "v"(a), "v"(b), "v"(c));
  return d;
#else
  return c;  // host stub, never executed
#endif
}

static __device__ __forceinline__ short f2bf(float f) {
  union { float f; unsigned u; } v; v.f = f;
  unsigned r = v.u + 0x7fffu + ((v.u >> 16) & 1u);
  return (short)(r >> 16);
}
static __device__ __forceinline__ float bf2f(short s) {
  union { unsigned u; float f; } v; v.u = ((unsigned)(unsigned short)s) << 16;
  return v.f;
}
static __device__ __forceinline__ unsigned cvtpk(float lo, float hi) {
  unsigned r;
  asm("v_cvt_pk_bf16_f32 %0, %1, %2" : "=v"(r) : "v"(lo), "v"(hi));
  return r;
}
static __device__ __forceinline__ float max3f(float a, float b, float c) {
  float r;
  asm("v_max3_f32 %0, %1, %2, %3" : "=v"(r) : "v"(a), "v"(b), "v"(c));
  return r;
}
static __device__ __forceinline__ bf16x4 pack4(unsigned w01, unsigned w23) {
  union { unsigned u[2]; bf16x4 v; } x;
  x.u[0] = w01; x.u[1] = w23;
  return x.v;
}

// ---------------------------------------------------------------------------
// Wtf: fragment-contiguous B layout (unchanged).
// ---------------------------------------------------------------------------
__global__ __launch_bounds__(256) void wt_kernel(
    const float* __restrict__ Wq, const float* __restrict__ Wk,
    const float* __restrict__ Wv, short* __restrict__ Wtf) {
  __shared__ float t[64][65];
  int bid = blockIdx.x;
  int mat = bid >> 4;
  int et  = bid & 15;
  int e0  = et * 64;
  const float* W = (mat == 0) ? Wq : (mat == 1) ? Wk : Wv;
  int c  = threadIdx.x & 63;
  int r0 = threadIdx.x >> 6;
#pragma unroll
  for (int i = 0; i < 16; ++i)
    t[i * 4 + r0][c] = W[(size_t)(e0 + i * 4 + r0) * HD + c];
  __syncthreads();
#pragma unroll
  for (int half = 0; half < 2; ++half) {
    int cid  = half * 256 + threadIdx.x;
    int ct4  = cid >> 7;
    int ksl  = (cid >> 6) & 1;
    int lane = cid & 63;
    int g    = lane >> 4;
    int mi   = lane & 15;
    int ct   = mat * 4 + ct4;
    int ks   = et * 2 + ksl;
    bf16x8 v;
#pragma unroll
    for (int j = 0; j < 8; ++j)
      v[j] = f2bf(t[ksl * 32 + 8 * g + j][ct4 * 16 + mi]);
    *(bf16x8*)(Wtf + ((size_t)(ct * 32 + ks) * 64 + lane) * 8) = v;
  }
}

// ---------------------------------------------------------------------------
// QKV projection, restructured: BM=16, grid 1024 (4 blocks/CU, 16 waves/CU).
// Whole X tile staged once to 32KB LDS in fragment order [ks][lane] with
// XOR-swizzle (conflict-free b128 reads). Each wave owns 3 of 12 col-tiles
// over the FULL K=1024 (no split-K combine). 3 barriers total.
// Epilogue reuses xs as the f32 part buffer (union).
// ---------------------------------------------------------------------------
__global__ __launch_bounds__(256, 4) void qkv_kernel(
    const float* __restrict__ X, const short* __restrict__ Wtf,
    const float* __restrict__ bq, const float* __restrict__ bk, const float* __restrict__ bv,
    short* __restrict__ Qf, short* __restrict__ Kf, short* __restrict__ Vf) {
  __shared__ __align__(16) short xs[16384];   // 32 KB; reused as part[12][4][64] f32

  int tid  = threadIdx.x;
  int w    = tid >> 6;
  int lane = tid & 63;
  int rowbase = blockIdx.x * 16;

  // ---- stage: 16 rows x 1024 k -> bf16 fragments [ks][lane(g*16+row)][8] ----
  {
    int row = w * 4 + (lane >> 4);
    int kb  = (lane & 15) * 4;
    const float* xrow = X + (size_t)(rowbase + row) * EMB;
#pragma unroll 4
    for (int i = 0; i < 16; ++i) {
      int k = i * 64 + kb;
      float4 xv = *(const float4*)(xrow + k);
      bf16x4 v;
      v[0] = f2bf(xv.x); v[1] = f2bf(xv.y); v[2] = f2bf(xv.z); v[3] = f2bf(xv.w);
      int ks = k >> 5, gg = (k >> 3) & 3, jh = (k >> 2) & 1;
      int sidx = ks * 512 + ((((gg * 16 + row) * 8) ^ ((ks & 7) << 3)) + jh * 4);
      *(bf16x4*)(&xs[sidx]) = v;
    }
  }
  __syncthreads();

  // ---- compute: wave w owns ct = w*3 .. w*3+2 over full K ----
  f32x4 acc[3];
#pragma unroll
  for (int i = 0; i < 3; ++i) acc[i] = (f32x4){0.f, 0.f, 0.f, 0.f};
  const short* wb = Wtf + ((size_t)(w * 3) * 32) * 512 + lane * 8;
#pragma unroll 4
  for (int ks = 0; ks < 32; ++ks) {
    bf16x8 af = *(const bf16x8*)(&xs[ks * 512 + ((lane * 8) ^ ((ks & 7) << 3))]);
#pragma unroll
    for (int i = 0; i < 3; ++i) {
      bf16x8 bfr = *(const bf16x8*)(wb + ((size_t)(i * 32 + ks)) * 512);
      acc[i] = __builtin_amdgcn_mfma_f32_16x16x32_bf16(af, bfr, acc[i], 0, 0, 0);
    }
  }
  __syncthreads();   // xs reads done; safe to overwrite as part

  float* part = (float*)xs;   // [ct][r][lane] = [12][4][64]
#pragma unroll
  for (int i = 0; i < 3; ++i) {
    int ct = w * 3 + i;
#pragma unroll
    for (int r = 0; r < 4; ++r) part[(ct * 4 + r) * 64 + lane] = acc[i][r];
  }
  __syncthreads();

  // ---- epilogue: fragment-packed stores ----
  int b_  = rowbase >> 12;
  int srb = rowbase & (SEQ - 1);
  int tgl = srb >> 4;
  int c32 = srb >> 5;
  int hl  = (srb >> 4) & 1;

  {  // Q or K: thread = (qk, kh, ln)
    int qk  = tid >> 7;
    int kh  = (tid >> 6) & 1;
    int ln  = tid & 63;
    int gg  = ln >> 4;
    int mi2 = ln & 15;
    const float* bp = qk ? bk : bq;
    bf16x8 v;
#pragma unroll
    for (int j = 0; j < 8; ++j) {
      int hd = kh * 32 + 8 * gg + j;
      int ct = qk * 4 + (hd >> 4);
      int cc = hd & 15;
      int li = (mi2 >> 2) * 16 + cc;
      int r2 = mi2 & 3;
      v[j] = f2bf(part[(ct * 4 + r2) * 64 + li] + bp[hd]);
    }
    size_t chunk = ((size_t)(b_ * 256 + tgl) * 2 + kh) * 512 + ln * 8;
    *(bf16x8*)((qk ? Kf : Qf) + chunk) = v;
  }
  {  // V: thread = (ht, ln); this block provides half hl of the c32 chunk
    int ht  = tid >> 6;
    int ln  = tid & 63;
    int gg  = ln >> 4;
    int mi2 = ln & 15;
    float bias = bv[ht * 16 + mi2];
    bf16x4 vv;
#pragma unroll
    for (int j = 0; j < 4; ++j)
      vv[j] = f2bf(part[((8 + ht) * 4 + j) * 64 + gg * 16 + mi2] + bias);
    *(bf16x4*)(Vf + ((size_t)(b_ * 128 + c32) * 4 + ht) * 512 + ln * 8 + hl * 4) = vv;
  }
}

// ---------------------------------------------------------------------------
// Flash attention (unchanged from R7): XCD batch-pinning, fragment-contiguous
// loads, register-resident P -> 16x16x16 PV MFMA, 8 waves/block.
// ---------------------------------------------------------------------------
__global__ __launch_bounds__(512, 4) void attn_kernel(
    const short* __restrict__ Qf, const short* __restrict__ Kf,
    const short* __restrict__ Vf, float* __restrict__ out) {
  __shared__ short lds_o[8][64][17];
  __shared__ float lds_m[8][16];
  __shared__ float lds_l[8][16];

  int tid  = threadIdx.x;
  int w    = tid >> 6;
  int lane = tid & 63;
  int g    = lane >> 4;
  int qi   = lane & 15;

  int bid = blockIdx.x;
  int bb  = bid & 3;
  int jj  = (bid >> 3) + (((bid >> 2) & 1) << 6);

  const float K1 = 0.125f * LOG2E;

  for (int ph = 0; ph < 2; ++ph) {
    int t  = ph ? (255 - jj) : jj;
    int q0 = t * 16;
    int row = q0 + qi;

    const short* qp = Qf + ((size_t)(bb * 256 + t) * 2) * 512 + lane * 8;
    bf16x8 qf0 = *(const bf16x8*)(qp);
    bf16x8 qf1 = *(const bf16x8*)(qp + 512);

    int total64 = (t + 4) >> 2;
    int blo = (w * total64) >> 3;
    int bhi = ((w + 1) * total64) >> 3;

    float m2 = -INFINITY, lsum = 0.f;
    f32x4 o[4];
#pragma unroll
    for (int i = 0; i < 4; ++i) o[i] = (f32x4){0.f, 0.f, 0.f, 0.f};

    for (int b = blo; b < bhi; ++b) {
      int kv0 = b * 64;
      const short* kp = Kf + ((size_t)(bb * 256 + 4 * b) * 2) * 512 + lane * 8;
      const short* vp = Vf + ((size_t)(bb * 128 + 2 * b) * 4) * 512 + lane * 8;

      bf16x8 kfa[4], kfb[4];
#pragma unroll
      for (int c = 0; c < 4; ++c) {
        kfa[c] = *(const bf16x8*)(kp + (c * 2) * 512);
        kfb[c] = *(const bf16x8*)(kp + (c * 2 + 1) * 512);
      }
      bf16x8 vv[8];
#pragma unroll
      for (int i = 0; i < 8; ++i) vv[i] = *(const bf16x8*)(vp + i * 512);

      f32x4 z[4];
      __builtin_amdgcn_s_setprio(1);
#pragma unroll
      for (int c = 0; c < 4; ++c) {
        f32x4 zz = (f32x4){0.f, 0.f, 0.f, 0.f};
        zz = __builtin_amdgcn_mfma_f32_16x16x32_bf16(kfa[c], qf0, zz, 0, 0, 0);
        zz = __builtin_amdgcn_mfma_f32_16x16x32_bf16(kfb[c], qf1, zz, 0, 0, 0);
        z[c] = zz;
      }
      __builtin_amdgcn_s_setprio(0);

      if (kv0 + 63 > q0) {
#pragma unroll
        for (int c = 0; c < 4; ++c)
#pragma unroll
          for (int r = 0; r < 4; ++r) {
            int col = kv0 + c * 16 + 4 * g + r;
            z[c][r] = (col <= row) ? z[c][r] : -INFINITY;
          }
      }

      float l1 = max3f(z[0][0], z[0][1], z[0][2]);
      float l2 = max3f(z[0][3], z[1][0], z[1][1]);
      float l3 = max3f(z[1][2], z[1][3], z[2][0]);
      float l4 = max3f(z[2][1], z[2][2], z[2][3]);
      float l5 = max3f(z[3][0], z[3][1], z[3][2]);
      float lmax = fmaxf(max3f(l1, l2, l3), max3f(l4, l5, z[3][3]));
      bool grow = __any(fmaf(lmax, K1, -8.0f) > m2);
      if (grow) {
        float gm = fmaxf(lmax, __shfl_xor(lmax, 16));
        gm = fmaxf(gm, __shfl_xor(gm, 32));
        float m2n = fmaxf(m2, gm * K1);
        float alpha = EXP2(m2 - m2n);
        m2 = m2n;
        lsum *= alpha;
#pragma unroll
        for (int i = 0; i < 4; ++i) {
          o[i][0] *= alpha; o[i][1] *= alpha; o[i][2] *= alpha; o[i][3] *= alpha;
        }
      }

      float ls = 0.f;
      bf16x4 pb[4];
#pragma unroll
      for (int c = 0; c < 4; ++c) {
        float p0 = EXP2(fmaf(z[c][0], K1, -m2));
        float p1 = EXP2(fmaf(z[c][1], K1, -m2));
        float p2 = EXP2(fmaf(z[c][2], K1, -m2));
        float p3 = EXP2(fmaf(z[c][3], K1, -m2));
        ls += (p0 + p1) + (p2 + p3);
        pb[c] = pack4(cvtpk(p0, p1), cvtpk(p2, p3));
      }
      lsum += ls;

      __builtin_amdgcn_s_setprio(1);
#pragma unroll
      for (int c = 0; c < 4; ++c) {
        int h2 = c >> 1;
#pragma unroll
        for (int ht = 0; ht < 4; ++ht) {
          bf16x8 vfull = vv[h2 * 4 + ht];
          bf16x4 va = (c & 1) ? __builtin_shufflevector(vfull, vfull, 4, 5, 6, 7)
                              : __builtin_shufflevector(vfull, vfull, 0, 1, 2, 3);
          o[ht] = MFMA16(va, pb[c], o[ht]);
        }
      }
      __builtin_amdgcn_s_setprio(0);
    }

    lsum += __shfl_xor(lsum, 16);
    lsum += __shfl_xor(lsum, 32);
#pragma unroll
    for (int ht = 0; ht < 4; ++ht)
#pragma unroll
      for (int r = 0; r < 4; ++r)
        lds_o[w][ht * 16 + 4 * g + r][qi] = f2bf(o[ht][r]);
    if (lane < 16) { lds_m[w][lane] = m2; lds_l[w][lane] = lsum; }
    __syncthreads();

    {
      int q  = tid >> 5;
      int c2 = tid & 31;
      int hb = c2 * 2;
      float mm = lds_m[0][q];
#pragma unroll
      for (int wv = 1; wv < 8; ++wv) mm = fmaxf(mm, lds_m[wv][q]);
      float denom = 0.f, a0 = 0.f, a1 = 0.f;
#pragma unroll
      for (int wv = 0; wv < 8; ++wv) {
        float e = EXP2(lds_m[wv][q] - mm);
        denom += lds_l[wv][q] * e;
        a0 += e * bf2f(lds_o[wv][hb][q]);
        a1 += e * bf2f(lds_o[wv][hb + 1][q]);
      }
      float inv = 1.f / denom;
      float2 res = make_float2(a0 * inv, a1 * inv);
      *(float2*)(out + ((size_t)(bb * SEQ + q0 + q)) * HD + hb) = res;
    }
    __syncthreads();
  }
}

// ---------------------------------------------------------------------------
extern "C" void kernel_launch(void* const* d_in, const int* in_sizes, int n_in,
                              void* d_out, int out_size, void* d_ws, size_t ws_size,
                              hipStream_t stream) {
  const float* X  = (const float*)d_in[0];
  const float* Wq = (const float*)d_in[1];
  const float* bq = (const float*)d_in[2];
  const float* Wk = (const float*)d_in[3];
  const float* bk = (const float*)d_in[4];
  const float* Wv = (const float*)d_in[5];
  const float* bv = (const float*)d_in[6];
  float* out = (float*)d_out;

  char* ws = (char*)d_ws;
  const size_t SZ = (size_t)NROW * HD * 2;
  short* Qf  = (short*)(ws);
  short* Kf  = (short*)(ws + SZ);
  short* Vf  = (short*)(ws + 2 * SZ);
  short* Wtf = (short*)(ws + 3 * SZ);

  wt_kernel<<<48, 256, 0, stream>>>(Wq, Wk, Wv, Wtf);
  qkv_kernel<<<NROW / 16, 256, 0, stream>>>(X, Wtf, bq, bk, bv, Qf, Kf, Vf);
  attn_kernel<<<BATCH * 128, 512, 0, stream>>>(Qf, Kf, Vf, out);
}